// Round 6
// baseline (167.639 us; speedup 1.0000x reference)
//
#include <hip/hip_runtime.h>

#define BB 4
#define NN 4
#define TT 4
#define AA 128
#define DD 64
#define HWD 36864              // 192*192
#define NG (BB * TT * AA)      // 2048
#define SL 128                 // slabs per image
#define SPTS (HWD / SL)        // 288 points per slab
#define NBLK (BB * TT * SL)    // 2048 blocks

__device__ __constant__ int c_ti[4] = {0, 0, 0, 1};
__device__ __constant__ int c_tj[4] = {1, 1, 2, 2};
__device__ __constant__ int c_tk[4] = {2, 3, 3, 3};

// ---------------------------------------------------------------------------
// K1: block (bt, slab), 128 threads (one query each). Stage SPTS points of
// image tj into LDS as (x,y,z,|p|^2); every lane scans the slab via uniform
// LDS broadcast reads. Key = s2 - 2*dot (order-equivalent; per-query |q|^2
// added at combine). Also zeroes K2's chain counters (block 0).
// ---------------------------------------------------------------------------
__global__ __launch_bounds__(128, 4) void
scan1_kernel(const float* __restrict__ pts,
             const int* __restrict__ anchor_idx,
             float* __restrict__ pkey1,
             int* __restrict__ pidx1,
             int* __restrict__ ctrs) {
#pragma clang fp contract(off)
    const int tid = threadIdx.x;
    if (blockIdx.x == 0 && tid < 17) ctrs[tid] = 0;   // ctrs[0..15]=per-bt, [16]=grid

    const int slab = blockIdx.x & (SL - 1);
    const int bt = blockIdx.x >> 7;
    const int t = bt & 3;
    const int b = bt >> 2;
    const int g = bt * AA + tid;

    __shared__ float4 spts[SPTS];
    {
        const float* src =
            pts + ((long)(b * NN + c_tj[t]) * HWD + slab * SPTS) * 3;
        for (int p = tid; p < SPTS; p += 128) {
            const float x = src[p * 3 + 0];
            const float y = src[p * 3 + 1];
            const float z = src[p * 3 + 2];
            spts[p] = make_float4(x, y, z, x * x + y * y + z * z);
        }
    }
    __syncthreads();

    const int qpix = anchor_idx[g];
    const float* qp = pts + ((long)(b * NN + c_ti[t]) * HWD + qpix) * 3;
    const float m2x = -2.0f * qp[0];
    const float m2y = -2.0f * qp[1];
    const float m2z = -2.0f * qp[2];

    float best = 3.4e38f;
    int besti = 0;
#pragma unroll 4
    for (int p = 0; p < SPTS; ++p) {
        const float4 P = spts[p];
        const float key = fmaf(P.x, m2x, fmaf(P.y, m2y, fmaf(P.z, m2z, P.w)));
        if (key < best) { best = key; besti = p; }   // ascending -> first occ
    }
    pkey1[slab * NG + g] = best;
    pidx1[slab * NG + g] = slab * SPTS + besti;
}

// ---------------------------------------------------------------------------
// K2: block (bt, slab), 128 threads (one query each).
//   a) combine1 in-register (key-only slab scan, coalesced; winner idx
//      fetched once; first-min-slab => first occurrence).
//   b) scan2 of image tk with query = pts_j[idx_j] (LDS-staged slab).
//   c) chained finisher: last block of each bt does combine2 + dki +
//      feature SE + per-bt reduce; last finisher overall writes the scalar.
// No global min_ij/idx_j needed: each lane carries its own combine1 results.
// ---------------------------------------------------------------------------
__global__ __launch_bounds__(128, 4) void
scan2_fused_kernel(const float* __restrict__ pts,
                   const float* __restrict__ feats,
                   const int* __restrict__ anchor_idx,
                   const float* __restrict__ pkey1,
                   const int* __restrict__ pidx1,
                   float* __restrict__ pkey2,
                   int* __restrict__ pidx2,
                   float* __restrict__ loss_bt,
                   float* __restrict__ batch_ok,
                   int* __restrict__ ctrs,
                   float* __restrict__ out) {
#pragma clang fp contract(off)
    const int tid = threadIdx.x;
    const int slab = blockIdx.x & (SL - 1);
    const int bt = blockIdx.x >> 7;
    const int t = bt & 3;
    const int b = bt >> 2;
    const int g = bt * AA + tid;
    const int i_img = c_ti[t];
    const int j_img = c_tj[t];
    const int k_img = c_tk[t];

    __shared__ float4 spts[SPTS];
    __shared__ float aps[AA][3];
    __shared__ float sred[2][AA];
    __shared__ int s_last;

    // ---- combine1 (redundant per block; lane owns query g) ----
    float bk = 3.4e38f;
    int sw = 0;
#pragma unroll 4
    for (int c = 0; c < SL; ++c) {
        const float k = pkey1[c * NG + g];
        if (k < bk) { bk = k; sw = c; }   // ascending c -> first occurrence
    }
    const int ij = pidx1[sw * NG + g];

    // anchor coords, min_ij (kept in registers for the finisher)
    const int ai = anchor_idx[g];
    const float* ap = pts + ((long)(b * NN + i_img) * HWD + ai) * 3;
    const float ax = ap[0], ay = ap[1], az = ap[2];
    const float minij = sqrtf(fmaxf(bk + (ax * ax + ay * ay + az * az), 0.0f));

    // chosen j-point coords
    const float* jp = pts + ((long)(b * NN + j_img) * HWD + ij) * 3;
    const float jx = jp[0], jy = jp[1], jz = jp[2];
    const float sqj = jx * jx + jy * jy + jz * jz;

    // ---- stage slab of image tk, scan2 ----
    {
        const float* src =
            pts + ((long)(b * NN + k_img) * HWD + slab * SPTS) * 3;
        for (int p = tid; p < SPTS; p += 128) {
            const float x = src[p * 3 + 0];
            const float y = src[p * 3 + 1];
            const float z = src[p * 3 + 2];
            spts[p] = make_float4(x, y, z, x * x + y * y + z * z);
        }
    }
    __syncthreads();

    const float m2x = -2.0f * jx;
    const float m2y = -2.0f * jy;
    const float m2z = -2.0f * jz;
    float best = 3.4e38f;
    int besti = 0;
#pragma unroll 4
    for (int p = 0; p < SPTS; ++p) {
        const float4 P = spts[p];
        const float key = fmaf(P.x, m2x, fmaf(P.y, m2y, fmaf(P.z, m2z, P.w)));
        if (key < best) { best = key; besti = p; }
    }
    pkey2[slab * NG + g] = best;
    pidx2[slab * NG + g] = slab * SPTS + besti;

    // ---- chained finisher: last block of this bt ----
    __threadfence();            // release own partial stores device-wide
    __syncthreads();
    if (tid == 0) s_last = (atomicAdd(&ctrs[bt], 1) == SL - 1) ? 1 : 0;
    __syncthreads();
    if (!s_last) return;
    __threadfence();            // acquire: see all blocks' partials

    // combine2 for lane's query
    float bk2 = 3.4e38f;
    int sw2 = 0;
#pragma unroll 4
    for (int c = 0; c < SL; ++c) {
        const float k = pkey2[c * NG + g];
        if (k < bk2) { bk2 = k; sw2 = c; }
    }
    const int ikg = pidx2[sw2 * NG + g];
    const float minjk = sqrtf(fmaxf(bk2 + sqj, 0.0f));

    // dki: query = chosen k-point, scan 128 anchors in LDS
    aps[tid][0] = ax;
    aps[tid][1] = ay;
    aps[tid][2] = az;
    const float* kp = pts + ((long)(b * NN + k_img) * HWD + ikg) * 3;
    const float kx = kp[0], ky = kp[1], kz = kp[2];
    const float sk = kx * kx + ky * ky + kz * kz;
    __syncthreads();

    float bd = 3.4e38f;
    int bi = 0;
    for (int a2 = 0; a2 < AA; ++a2) {
        const float qx = aps[a2][0], qy = aps[a2][1], qz = aps[a2][2];
        const float s2 = qx * qx + qy * qy + qz * qz;
        const float dot = kx * qx + ky * qy + kz * qz;
        const float d2 = (sk + s2) - 2.0f * dot;
        if (d2 < bd) { bd = d2; bi = a2; }
    }
    const float minki = sqrtf(fmaxf(bd, 0.0f));

    const int valid = (minij < 0.3f) && (minjk < 0.3f) && (minki < 0.3f);

    // feature SE (reference quirk: fr row = raw pixel index bi in [0,128)).
    // float4 loads; accumulation order identical to the scalar d-loop.
    const float4* fr4 =
        (const float4*)(feats + ((long)(b * NN + i_img) * HWD + bi) * DD);
    const float4* fa4 =
        (const float4*)(feats + ((long)(b * NN + i_img) * HWD + ai) * DD);
    float snr = 0.0f, sna = 0.0f;
#pragma unroll
    for (int r = 0; r < 16; ++r) {
        const float4 v = fr4[r];
        snr = snr + v.x * v.x; snr = snr + v.y * v.y;
        snr = snr + v.z * v.z; snr = snr + v.w * v.w;
    }
#pragma unroll
    for (int r = 0; r < 16; ++r) {
        const float4 v = fa4[r];
        sna = sna + v.x * v.x; sna = sna + v.y * v.y;
        sna = sna + v.z * v.z; sna = sna + v.w * v.w;
    }
    const float nr = fmaxf(sqrtf(snr), 1e-12f);
    const float na = fmaxf(sqrtf(sna), 1e-12f);
    float se = 0.0f;
#pragma unroll
    for (int r = 0; r < 16; ++r) {
        const float4 u = fr4[r];
        const float4 v = fa4[r];
        float x;
        x = u.x / nr - v.x / na; se = se + x * x;
        x = u.y / nr - v.y / na; se = se + x * x;
        x = u.z / nr - v.z / na; se = se + x * x;
        x = u.w / nr - v.w / na; se = se + x * x;
    }

    sred[0][tid] = (float)valid;
    sred[1][tid] = valid ? se : 0.0f;
    __syncthreads();
    for (int s = 64; s > 0; s >>= 1) {
        if (tid < s) {
            sred[0][tid] += sred[0][tid + s];
            sred[1][tid] += sred[1][tid + s];
        }
        __syncthreads();
    }
    if (tid == 0) {
        const float cnt = sred[0][0];
        const float lbt = (cnt > 0.0f)
                              ? sred[1][0] / (fmaxf(cnt, 1.0f) * (float)DD)
                              : 0.0f;
        const float ok = (cnt >= 5.0f) ? 1.0f : 0.0f;
        atomicExch(&loss_bt[bt], lbt);     // coherence-point write
        atomicExch(&batch_ok[bt], ok);
        __threadfence();
        const int old = atomicAdd(&ctrs[16], 1);
        if (old == 15) {
            float s = 0.0f;
            for (int tt = 0; tt < TT; ++tt) {
                float tc = 0.0f, sl = 0.0f;
                for (int bb = 0; bb < BB; ++bb) {
                    const float okv = atomicAdd(&batch_ok[bb * TT + tt], 0.0f);
                    const float lv = atomicAdd(&loss_bt[bb * TT + tt], 0.0f);
                    tc += okv;
                    sl += lv * okv;
                }
                s += (tc > 0.0f) ? sl / fmaxf(tc, 1.0f) : 0.0f;
            }
            out[0] = s / (float)TT;
        }
    }
}

extern "C" void kernel_launch(void* const* d_in, const int* in_sizes, int n_in,
                              void* d_out, int out_size, void* d_ws,
                              size_t ws_size, hipStream_t stream) {
    const float* feats = (const float*)d_in[0];   // (B,N,H,W,D) f32
    const float* pts = (const float*)d_in[1];     // (B,N,H,W,3) f32
    const int* anchor = (const int*)d_in[2];      // (B,T,A) i32
    float* out = (float*)d_out;

    float* ws = (float*)d_ws;
    float* pkey1 = ws;                               // SL*NG f32 (1 MB)
    int* pidx1 = (int*)(ws + SL * NG);
    float* pkey2 = ws + 2 * SL * NG;
    int* pidx2 = (int*)(ws + 3 * SL * NG);
    float* loss_bt = ws + 4 * SL * NG;               // 16
    float* batch_ok = loss_bt + 16;                  // 16
    int* ctrs = (int*)(batch_ok + 16);               // 17 ints

    scan1_kernel<<<NBLK, 128, 0, stream>>>(pts, anchor, pkey1, pidx1, ctrs);
    scan2_fused_kernel<<<NBLK, 128, 0, stream>>>(pts, feats, anchor, pkey1,
                                                 pidx1, pkey2, pidx2, loss_bt,
                                                 batch_ok, ctrs, out);
}

// Round 7
// 119.318 us; speedup vs baseline: 1.4050x; 1.4050x over previous
//
#include <hip/hip_runtime.h>

#define BB 4
#define NN 4
#define TT 4
#define AA 128
#define DD 64
#define HWD 36864              // 192*192
#define NG (BB * TT * AA)      // 2048
#define SL 128                 // slabs per image
#define SPTS (HWD / SL)        // 288 points per slab
#define NBLK (BB * TT * SL)    // 2048 blocks

__device__ __constant__ int c_ti[4] = {0, 0, 0, 1};
__device__ __constant__ int c_tj[4] = {1, 1, 2, 2};
__device__ __constant__ int c_tk[4] = {2, 3, 3, 3};

// ---------------------------------------------------------------------------
// K1: block (bt, slab) = 64 threads (1 wave). Lane owns TWO queries (tid,
// tid+64). Stage SPTS points of image tj into LDS as (x,y,z,|p|^2); scan via
// uniform LDS broadcast (one b128 per point serves 128 pairs — half the LDS
// traffic of the 2-wave variant). Key = s2 - 2*dot (order-equivalent).
// ---------------------------------------------------------------------------
__global__ __launch_bounds__(64) void
scan1_kernel(const float* __restrict__ pts,
             const int* __restrict__ anchor_idx,
             float* __restrict__ pkey1,
             int* __restrict__ pidx1) {
#pragma clang fp contract(off)
    const int tid = threadIdx.x;          // 0..63
    const int slab = blockIdx.x & (SL - 1);
    const int bt = blockIdx.x >> 7;
    const int t = bt & 3;
    const int b = bt >> 2;
    const int g0 = bt * AA + tid;
    const int g1 = g0 + 64;

    __shared__ float4 spts[SPTS];
    {
        const float* src =
            pts + ((long)(b * NN + c_tj[t]) * HWD + slab * SPTS) * 3;
        for (int p = tid; p < SPTS; p += 64) {
            const float x = src[p * 3 + 0];
            const float y = src[p * 3 + 1];
            const float z = src[p * 3 + 2];
            spts[p] = make_float4(x, y, z, x * x + y * y + z * z);
        }
    }
    __syncthreads();

    const long ibase = (long)(b * NN + c_ti[t]) * HWD;
    const float* qp0 = pts + (ibase + anchor_idx[g0]) * 3;
    const float* qp1 = pts + (ibase + anchor_idx[g1]) * 3;
    const float m2x0 = -2.0f * qp0[0], m2y0 = -2.0f * qp0[1], m2z0 = -2.0f * qp0[2];
    const float m2x1 = -2.0f * qp1[0], m2y1 = -2.0f * qp1[1], m2z1 = -2.0f * qp1[2];

    float best0 = 3.4e38f, best1 = 3.4e38f;
    int bi0 = 0, bi1 = 0;
#pragma unroll 4
    for (int p = 0; p < SPTS; ++p) {
        const float4 P = spts[p];
        const float k0 = fmaf(P.x, m2x0, fmaf(P.y, m2y0, fmaf(P.z, m2z0, P.w)));
        const float k1 = fmaf(P.x, m2x1, fmaf(P.y, m2y1, fmaf(P.z, m2z1, P.w)));
        if (k0 < best0) { best0 = k0; bi0 = p; }   // ascending -> first occ
        if (k1 < best1) { best1 = k1; bi1 = p; }
    }
    pkey1[slab * NG + g0] = best0;
    pidx1[slab * NG + g0] = slab * SPTS + bi0;
    pkey1[slab * NG + g1] = best1;
    pidx1[slab * NG + g1] = slab * SPTS + bi1;
}

// ---------------------------------------------------------------------------
// K2: same grid/shape. Combine1 in-register (key-only slab scan, coalesced;
// winner slab's idx fetched once; first-min-slab => first occurrence; pkey1
// visible via K1's kernel-boundary release — NO fences here). slab==0 blocks
// publish min_ij/idx_j. Then scan image tk with query = pts_j[idx_j].
// Block 0 zeroes K3's finish counter.
// ---------------------------------------------------------------------------
__global__ __launch_bounds__(64) void
scan2_kernel(const float* __restrict__ pts,
             const int* __restrict__ anchor_idx,
             const float* __restrict__ pkey1,
             const int* __restrict__ pidx1,
             float* __restrict__ min_ij,
             int* __restrict__ idx_j_out,
             float* __restrict__ pkey2,
             int* __restrict__ pidx2,
             int* __restrict__ ctr) {
#pragma clang fp contract(off)
    const int tid = threadIdx.x;
    const int slab = blockIdx.x & (SL - 1);
    const int bt = blockIdx.x >> 7;
    const int t = bt & 3;
    const int b = bt >> 2;
    const int g0 = bt * AA + tid;
    const int g1 = g0 + 64;

    if (blockIdx.x == 0 && tid == 0) ctr[0] = 0;

    // combine1: key-only scan over slabs, then one idx fetch per query
    float bk0 = 3.4e38f, bk1 = 3.4e38f;
    int s0 = 0, s1 = 0;
#pragma unroll 4
    for (int c = 0; c < SL; ++c) {
        const float k0 = pkey1[c * NG + g0];
        const float k1 = pkey1[c * NG + g1];
        if (k0 < bk0) { bk0 = k0; s0 = c; }   // ascending c -> first occ
        if (k1 < bk1) { bk1 = k1; s1 = c; }
    }
    const int ij0 = pidx1[s0 * NG + g0];
    const int ij1 = pidx1[s1 * NG + g1];

    if (slab == 0) {
        const long ibase = (long)(b * NN + c_ti[t]) * HWD;
        {
            const float* qp = pts + (ibase + anchor_idx[g0]) * 3;
            const float x = qp[0], y = qp[1], z = qp[2];
            min_ij[g0] = sqrtf(fmaxf(bk0 + (x * x + y * y + z * z), 0.0f));
            idx_j_out[g0] = ij0;
        }
        {
            const float* qp = pts + (ibase + anchor_idx[g1]) * 3;
            const float x = qp[0], y = qp[1], z = qp[2];
            min_ij[g1] = sqrtf(fmaxf(bk1 + (x * x + y * y + z * z), 0.0f));
            idx_j_out[g1] = ij1;
        }
    }

    // stage slab of image tk
    __shared__ float4 spts[SPTS];
    {
        const float* src =
            pts + ((long)(b * NN + c_tk[t]) * HWD + slab * SPTS) * 3;
        for (int p = tid; p < SPTS; p += 64) {
            const float x = src[p * 3 + 0];
            const float y = src[p * 3 + 1];
            const float z = src[p * 3 + 2];
            spts[p] = make_float4(x, y, z, x * x + y * y + z * z);
        }
    }
    __syncthreads();

    // scan2: queries = chosen points of image tj
    const long jbase = (long)(b * NN + c_tj[t]) * HWD;
    const float* jp0 = pts + (jbase + ij0) * 3;
    const float* jp1 = pts + (jbase + ij1) * 3;
    const float m2x0 = -2.0f * jp0[0], m2y0 = -2.0f * jp0[1], m2z0 = -2.0f * jp0[2];
    const float m2x1 = -2.0f * jp1[0], m2y1 = -2.0f * jp1[1], m2z1 = -2.0f * jp1[2];

    float best0 = 3.4e38f, best1 = 3.4e38f;
    int bi0 = 0, bi1 = 0;
#pragma unroll 4
    for (int p = 0; p < SPTS; ++p) {
        const float4 P = spts[p];
        const float k0 = fmaf(P.x, m2x0, fmaf(P.y, m2y0, fmaf(P.z, m2z0, P.w)));
        const float k1 = fmaf(P.x, m2x1, fmaf(P.y, m2y1, fmaf(P.z, m2z1, P.w)));
        if (k0 < best0) { best0 = k0; bi0 = p; }
        if (k1 < best1) { best1 = k1; bi1 = p; }
    }
    pkey2[slab * NG + g0] = best0;
    pidx2[slab * NG + g0] = slab * SPTS + bi0;
    pkey2[slab * NG + g1] = best1;
    pidx2[slab * NG + g1] = slab * SPTS + bi1;
}

// ---------------------------------------------------------------------------
// K3: 16 blocks (one per bt), 128 threads (one per anchor). Verbatim from
// round 5 (passed): combine2 -> min_jk/idx_k; dki vs LDS-staged anchors;
// feature SE; block reduce; finish-counter; last block -> scalar.
// ---------------------------------------------------------------------------
__global__ __launch_bounds__(128) void
pass3_kernel(const float* __restrict__ pts,
             const float* __restrict__ feats,
             const int* __restrict__ anchor_idx,
             const float* __restrict__ min_ij,
             const int* __restrict__ idx_j_in,
             const float* __restrict__ pkey2,
             const int* __restrict__ pidx2,
             float* __restrict__ loss_bt,
             float* __restrict__ batch_ok,
             int* __restrict__ ctr,
             float* __restrict__ out) {
#pragma clang fp contract(off)
    const int bt = blockIdx.x;
    const int t = bt & 3;
    const int b = bt >> 2;
    const int i = c_ti[t];
    const int k = c_tk[t];
    const int tid = threadIdx.x;
    const int g = bt * AA + tid;

    // combine2
    float bkey = 3.4e38f;
    int ik = 0;
    for (int c = 0; c < SL; ++c) {
        const float kk = pkey2[c * NG + g];
        const int ii = pidx2[c * NG + g];
        if (kk < bkey) { bkey = kk; ik = ii; }
    }
    const int qpj = idx_j_in[g];
    const float* jp = pts + ((long)(b * NN + c_tj[t]) * HWD + qpj) * 3;
    const float jx = jp[0], jy = jp[1], jz = jp[2];
    const float min_jk =
        sqrtf(fmaxf(bkey + (jx * jx + jy * jy + jz * jz), 0.0f));

    // dki
    const int ai = anchor_idx[g];
    const float* ap = pts + ((long)(b * NN + i) * HWD + ai) * 3;
    __shared__ float aps[AA][3];
    aps[tid][0] = ap[0];
    aps[tid][1] = ap[1];
    aps[tid][2] = ap[2];
    const float* kp = pts + ((long)(b * NN + k) * HWD + ik) * 3;
    const float kx = kp[0], ky = kp[1], kz = kp[2];
    const float sk = kx * kx + ky * ky + kz * kz;
    __syncthreads();

    float best = 3.4e38f;
    int besti = 0;
    for (int a2 = 0; a2 < AA; ++a2) {
        const float qx = aps[a2][0], qy = aps[a2][1], qz = aps[a2][2];
        const float s2 = qx * qx + qy * qy + qz * qz;
        const float dot = kx * qx + ky * qy + kz * qz;
        const float d2 = (sk + s2) - 2.0f * dot;
        if (d2 < best) { best = d2; besti = a2; }
    }
    const float min_ki = sqrtf(fmaxf(best, 0.0f));

    const int valid =
        (min_ij[g] < 0.3f) && (min_jk < 0.3f) && (min_ki < 0.3f);

    // feat_ret: reference quirk — raw pixel index besti in [0,128)
    const float* fr = feats + ((long)(b * NN + i) * HWD + besti) * DD;
    const float* fa = feats + ((long)(b * NN + i) * HWD + ai) * DD;
    float snr = 0.0f, sna = 0.0f;
    for (int d = 0; d < DD; ++d) { const float x = fr[d]; snr += x * x; }
    for (int d = 0; d < DD; ++d) { const float y = fa[d]; sna += y * y; }
    const float nr = fmaxf(sqrtf(snr), 1e-12f);
    const float na = fmaxf(sqrtf(sna), 1e-12f);
    float se = 0.0f;
    for (int d = 0; d < DD; ++d) {
        const float x = fr[d] / nr - fa[d] / na;
        se += x * x;
    }

    __shared__ float sred[2][AA];
    sred[0][tid] = (float)valid;
    sred[1][tid] = valid ? se : 0.0f;
    __syncthreads();
    for (int s = 64; s > 0; s >>= 1) {
        if (tid < s) {
            sred[0][tid] += sred[0][tid + s];
            sred[1][tid] += sred[1][tid + s];
        }
        __syncthreads();
    }
    if (tid == 0) {
        const float cnt = sred[0][0];
        const float lbt = (cnt > 0.0f)
                              ? sred[1][0] / (fmaxf(cnt, 1.0f) * (float)DD)
                              : 0.0f;
        const float ok = (cnt >= 5.0f) ? 1.0f : 0.0f;
        atomicExch(&loss_bt[bt], lbt);     // device-scope write-through
        atomicExch(&batch_ok[bt], ok);
        __threadfence();                   // only 16 blocks — amortized
        const int old = atomicAdd(ctr, 1);
        if (old == 15) {
            float s = 0.0f;
            for (int tt = 0; tt < TT; ++tt) {
                float tc = 0.0f, sl = 0.0f;
                for (int bb = 0; bb < BB; ++bb) {
                    const float okv = atomicAdd(&batch_ok[bb * TT + tt], 0.0f);
                    const float lv = atomicAdd(&loss_bt[bb * TT + tt], 0.0f);
                    tc += okv;
                    sl += lv * okv;
                }
                s += (tc > 0.0f) ? sl / fmaxf(tc, 1.0f) : 0.0f;
            }
            out[0] = s / (float)TT;
        }
    }
}

extern "C" void kernel_launch(void* const* d_in, const int* in_sizes, int n_in,
                              void* d_out, int out_size, void* d_ws,
                              size_t ws_size, hipStream_t stream) {
    const float* feats = (const float*)d_in[0];   // (B,N,H,W,D) f32
    const float* pts = (const float*)d_in[1];     // (B,N,H,W,3) f32
    const int* anchor = (const int*)d_in[2];      // (B,T,A) i32
    float* out = (float*)d_out;

    float* ws = (float*)d_ws;
    float* pkey1 = ws;                               // SL*NG f32 (1 MB)
    int* pidx1 = (int*)(ws + SL * NG);
    float* pkey2 = ws + 2 * SL * NG;
    int* pidx2 = (int*)(ws + 3 * SL * NG);
    float* min_ij = ws + 4 * SL * NG;                // NG
    int* idx_j = (int*)(min_ij + NG);                // NG
    float* loss_bt = min_ij + 2 * NG;                // 16
    float* batch_ok = loss_bt + 16;                  // 16
    int* ctr = (int*)(batch_ok + 16);                // 1

    scan1_kernel<<<NBLK, 64, 0, stream>>>(pts, anchor, pkey1, pidx1);
    scan2_kernel<<<NBLK, 64, 0, stream>>>(pts, anchor, pkey1, pidx1, min_ij,
                                          idx_j, pkey2, pidx2, ctr);
    pass3_kernel<<<BB * TT, 128, 0, stream>>>(pts, feats, anchor, min_ij,
                                              idx_j, pkey2, pidx2, loss_bt,
                                              batch_ok, ctr, out);
}